// Round 1
// 554.328 us; speedup vs baseline: 1.0103x; 1.0103x over previous
//
#include <hip/hip_runtime.h>
#include <hip/hip_bf16.h>

#define NB 2
#define NH 12
#define NS 256
#define NE 64
#define NC 768   // NH*NE
#define NL 25

#define CH 128     // c per chunk = 2 heads (head-aligned)
#define NCH 6      // NC / CH
#define TI 64      // i-rows per block
#define PAIRB 1040 // LDS bytes per i-row-pair: 1024 data + 16 pad (bank spread, 16B-aligned)

typedef __attribute__((ext_vector_type(8))) short short8;   // MFMA A/B frag (8 bf16)
typedef __attribute__((ext_vector_type(4))) float float4v;  // MFMA acc

__device__ __forceinline__ unsigned short bfb(float x) {
    __hip_bfloat16 h = __float2bfloat16(x);   // RNE
    return *reinterpret_cast<unsigned short*>(&h);
}
__device__ __forceinline__ unsigned int pk2(float x, float y) {
    return (unsigned int)bfb(x) | ((unsigned int)bfb(y) << 16);
}

// W (25x768 fp32) -> Wb (32x768 bf16, rows 25..31 zeroed for the padded M-tile)
__global__ void prep_w(const float* __restrict__ W, unsigned short* __restrict__ Wb) {
    int idx = blockIdx.x * 256 + threadIdx.x;
    if (idx >= 32 * NC) return;
    int row = idx / NC;
    int col = idx - row * NC;
    Wb[idx] = (row < NL) ? bfb(W[row * NC + col]) : (unsigned short)0;
}

// out[b,j,l,i] = bias[l] + sum_c W[l,c] * p[b,c>>6,i,j] * (rel[b,i,j,c] + v[b,c>>6,j,c&63])
// rel staged RAW (f32) via async global_load_lds (pure DMA, coalesced 512B runs);
// p and v folded into consumer-side fragment assembly (p uniform per fragment row).
__global__ __launch_bounds__(256, 2) void tmhs_mfma(
    const float* __restrict__ p,
    const float* __restrict__ v,
    const float* __restrict__ rel,
    const unsigned short* __restrict__ Wb,   // 32x768 bf16 (prepped)
    const float* __restrict__ bias,
    float* __restrict__ out)
{
    // double-buffered raw-f32 tile: 64 rows x 128 c, row-pairs contiguous (1 KB) + 16 B pad
    __shared__ __align__(16) unsigned char sF[2][32 * PAIRB];   // 2 x 33280 B -> 2 blocks/CU

    const int tid = threadIdx.x;
    const int bx  = blockIdx.x;          // 2048 = b(2) * iq(4) * j(256), j fastest (DRAM locality)
    const int j   = bx & 255;
    const int iq  = (bx >> 8) & 3;
    const int b   = bx >> 10;
    const int i0  = iq * TI;

    const int lane = tid & 63;
    const int wv   = tid >> 6;           // wave 0..3 -> i sub-range (stages exactly its own rows)
    const int n15  = lane & 15;
    const int quad = lane >> 4;
    const int l32  = lane & 31;
    const int rh   = lane >> 5;          // row parity within staged pair

    const int icol = i0 + wv * 16 + n15; // this lane's i (B-frag row == output col)

    // preload p[b,h,icol,j] for all 12 heads (L2/L3-hot, 4B scattered)
    float ph[NH];
#pragma unroll
    for (int h = 0; h < NH; ++h)
        ph[h] = p[((size_t)(b * NH + h) * NS + icol) * NS + j];

    float4v z = {0.f, 0.f, 0.f, 0.f};
    float4v acc[2] = {z, z};             // [mtile], accumulated across all K directly

    // LDS read addressing: row i at (i>>1)*1040 + (i&1)*512
    const int irow  = wv * 16 + n15;
    const int rbyte = (irow >> 1) * PAIRB + (irow & 1) * 512;
    const int qbase = wv * 8;            // this wave's 8 row-pairs

    // async DMA stage of chunk ch into buffer pb: 8 x global_load_lds dwordx4 per wave,
    // each = 2 x 512 B contiguous global segments -> LDS linear (base + lane*16)
    auto stage = [&](int pb, int ch) {
        const int kc = ch * CH;
#pragma unroll
        for (int s = 0; s < 8; ++s) {
            const int q   = qbase + s;
            const int row = i0 + q * 2 + rh;
            const float* gp = rel + ((size_t)(b * NS + row) * NS + j) * NC + kc + l32 * 4;
            __builtin_amdgcn_global_load_lds(
                (const __attribute__((address_space(1))) void*)gp,
                (__attribute__((address_space(3))) void*)(&sF[pb][q * PAIRB]),
                16, 0, 0);
        }
    };

    stage(0, 0);
    __syncthreads();                     // drains vmcnt -> tile 0 ready

#pragma unroll
    for (int ch = 0; ch < NCH; ++ch) {
        const int kc = ch * CH;
        const int pb = ch & 1;

        if (ch + 1 < NCH)
            stage((ch + 1) & 1, ch + 1); // prefetch next chunk; drains in end-of-iter sync

#pragma unroll
        for (int ks = 0; ks < 4; ++ks) { // 4 x K=32 per chunk; ks 0-1 head A, 2-3 head B
            // A-frag (W): row m = lane&15 (+16 for mtile1), k = quad*8 + 0..7. L1/L2-hot.
            short8 af0 = *(const short8*)(Wb + (     n15) * NC + kc + ks * 32 + quad * 8);
            short8 af1 = *(const short8*)(Wb + (16 + n15) * NC + kc + ks * 32 + quad * 8);

            // B-frag: raw f32 from LDS (conflict-optimal b128), + v, * p, cvt -> bf16x8
            const unsigned char* bp = &sF[pb][rbyte + ks * 128 + quad * 32];
            const float4 f0 = *(const float4*)bp;
            const float4 f1 = *(const float4*)(bp + 16);
            const float* vp = v + ((size_t)(b * NH + 2 * ch + (ks >> 1)) * NS + j) * NE
                              + (ks & 1) * 32 + quad * 8;
            const float4 v0 = *(const float4*)vp;
            const float4 v1 = *(const float4*)(vp + 4);
            const float  pr = ph[2 * ch + (ks >> 1)];   // uniform over the 8 k of this frag

            union { short8 s8; unsigned int u[4]; } bf;
            bf.u[0] = pk2(pr * (f0.x + v0.x), pr * (f0.y + v0.y));
            bf.u[1] = pk2(pr * (f0.z + v0.z), pr * (f0.w + v0.w));
            bf.u[2] = pk2(pr * (f1.x + v1.x), pr * (f1.y + v1.y));
            bf.u[3] = pk2(pr * (f1.z + v1.z), pr * (f1.w + v1.w));

            acc[0] = __builtin_amdgcn_mfma_f32_16x16x32_bf16(af0, bf.s8, acc[0], 0, 0, 0);
            acc[1] = __builtin_amdgcn_mfma_f32_16x16x32_bf16(af1, bf.s8, acc[1], 0, 0, 0);
        }

        // one barrier per chunk: waits prefetch (vmcnt) + protects buffer reuse (lgkmcnt)
        __syncthreads();
    }

    // Epilogue: C/D layout col(i) = lane&15, row(l) = quad*4 + reg (m89-verified).
    const size_t obase = ((size_t)(b * NS + j) * NL) * NS;
#pragma unroll
    for (int mt = 0; mt < 2; ++mt) {
#pragma unroll
        for (int r = 0; r < 4; ++r) {
            const int l = mt * 16 + quad * 4 + r;
            if (l < NL)
                out[obase + l * NS + icol] = acc[mt][r] + bias[l];
        }
    }
}

extern "C" void kernel_launch(void* const* d_in, const int* in_sizes, int n_in,
                              void* d_out, int out_size, void* d_ws, size_t ws_size,
                              hipStream_t stream) {
    const float* p    = (const float*)d_in[0];
    const float* v    = (const float*)d_in[1];
    const float* rel  = (const float*)d_in[2];
    const float* W    = (const float*)d_in[3];
    const float* bias = (const float*)d_in[4];
    float* out = (float*)d_out;
    unsigned short* Wb = (unsigned short*)d_ws;   // 32*768*2 = 48 KB scratch

    prep_w<<<dim3((32 * NC + 255) / 256), dim3(256), 0, stream>>>(W, Wb);
    tmhs_mfma<<<dim3(NB * 4 * NS), dim3(256), 0, stream>>>(p, v, rel, Wb, bias, out);
}